// Round 1
// baseline (5589.137 us; speedup 1.0000x reference)
//
#include <hip/hip_runtime.h>
#include <math.h>

namespace {
constexpr int Bn    = 64;
constexpr int CIN   = 320;
constexpr int COUT  = 640;
constexpr int CIN_G = 32;   // 320/10
constexpr int COUT_G= 64;   // 640/10
constexpr int NH    = 4;
constexpr int Dd    = 160;
constexpr int ALLOCC= 16;
constexpr int Hh    = 32, Wh = 32;
constexpr int Ss    = 1024; // 32*32
constexpr int QKV_CG= 64;   // 640/10
constexpr int QKV_OG= 192;  // 1920/10
constexpr float ATT_SCALE = 0.0395284707521047f; // 640^-0.5
}

// ---------------- K1: grouped conv3x3 + bias ----------------
__global__ __launch_bounds__(256) void conv3x3_k(
    const float* __restrict__ x, const float* __restrict__ w1,
    const float* __restrict__ b1, float* __restrict__ out) {
    int idx = blockIdx.x * 256 + threadIdx.x;
    int wx = idx & 31;
    int hy = (idx >> 5) & 31;
    int oc = (idx >> 10) % COUT;
    int b  = idx / (COUT * Ss);
    int g  = oc / COUT_G;
    const float* wp = w1 + (size_t)oc * CIN_G * 9;
    const float* xb = x + ((size_t)b * CIN + g * CIN_G) * Ss;
    float acc = b1[oc];
    for (int ic = 0; ic < CIN_G; ++ic) {
        const float* xc = xb + (size_t)ic * Ss;
        const float* wc = wp + ic * 9;
        #pragma unroll
        for (int dy = 0; dy < 3; ++dy) {
            int yy = hy + dy - 1;
            if (yy < 0 || yy >= Hh) continue;
            #pragma unroll
            for (int dx = 0; dx < 3; ++dx) {
                int xx = wx + dx - 1;
                if (xx < 0 || xx >= Wh) continue;
                acc += xc[yy * Wh + xx] * wc[dy * 3 + dx];
            }
        }
    }
    out[idx] = acc;
}

// ---------------- K2: BN stats -> scale/shift ----------------
__global__ __launch_bounds__(256) void bnstats_k(
    const float* __restrict__ conv, const float* __restrict__ gamma,
    const float* __restrict__ beta, float* __restrict__ scaleC,
    float* __restrict__ shiftC) {
    int c = blockIdx.x;
    double s = 0.0, s2 = 0.0;
    for (int e = threadIdx.x; e < Bn * Ss; e += 256) {
        int b = e >> 10, sp = e & 1023;
        float v = conv[((size_t)b * COUT + c) * Ss + sp];
        s += v; s2 += (double)v * v;
    }
    __shared__ double rs[256], rs2[256];
    rs[threadIdx.x] = s; rs2[threadIdx.x] = s2;
    __syncthreads();
    for (int off = 128; off > 0; off >>= 1) {
        if (threadIdx.x < off) { rs[threadIdx.x] += rs[threadIdx.x + off]; rs2[threadIdx.x] += rs2[threadIdx.x + off]; }
        __syncthreads();
    }
    if (threadIdx.x == 0) {
        double mean = rs[0] / (Bn * Ss);
        double var  = rs2[0] / (Bn * Ss) - mean * mean;
        float sc = gamma[c] * rsqrtf((float)var + 1e-5f);
        scaleC[c] = sc;
        shiftC[c] = beta[c] - (float)mean * sc;
    }
}

// ---------------- K3: zero attn region ----------------
__global__ __launch_bounds__(256) void zerof_k(float* __restrict__ p, int n) {
    int i = blockIdx.x * 256 + threadIdx.x;
    if (i < n) p[i] = 0.f;
}

// ---------------- K4: BN+ReLU fused grouped 1x1 -> q, k_sub, v_sub ----------------
__global__ __launch_bounds__(256) void qkv_k(
    const float* __restrict__ conv, const float* __restrict__ wqkv,
    const float* __restrict__ scaleC, const float* __restrict__ shiftC,
    const int* __restrict__ y,
    float* __restrict__ q, float* __restrict__ ksub, float* __restrict__ vsub) {
    int idx = blockIdx.x * 256 + threadIdx.x;
    int s    = idx & 1023;
    int rest = idx >> 10;
    int t = rest % 192;
    int h = (rest / 192) & 3;
    int b = rest / (192 * 4);
    int c_out; float* dst;
    if (t < 160) {
        c_out = h * Dd + t;
        dst = q + (((size_t)(b * NH + h) * Dd + t) * Ss + s);
    } else if (t < 176) {
        int jt = t - 160; int d = y[b] * ALLOCC + jt;
        c_out = 640 + h * Dd + d;
        dst = ksub + (((size_t)(b * NH + h) * ALLOCC + jt) * Ss + s);
    } else {
        int jt = t - 176; int d = y[b] * ALLOCC + jt;
        c_out = 1280 + h * Dd + d;
        dst = vsub + (((size_t)(b * NH + h) * ALLOCC + jt) * Ss + s);
    }
    int g = c_out / QKV_OG;
    const float* wp = wqkv + (size_t)c_out * QKV_CG;
    const float* op = conv + ((size_t)b * COUT + g * QKV_CG) * Ss + s;
    float acc = 0.f;
    for (int c = 0; c < QKV_CG; ++c) {
        int ch = g * QKV_CG + c;
        float v = op[(size_t)c * Ss];
        v = fmaxf(v * scaleC[ch] + shiftC[ch], 0.f);
        acc += wp[c] * v;
    }
    *dst = acc;
}

// ---------------- K5: attention per (b,h) block ----------------
__global__ __launch_bounds__(256) void attn_k(
    const float* __restrict__ q, const float* __restrict__ ksub,
    const float* __restrict__ vsub, const int* __restrict__ y,
    float* __restrict__ o, float* __restrict__ attn) {
    __shared__ float qv[160 * 68];   // phase1: q tile [160][68]; phase2: v tile [16][256]
    __shared__ float klds[16 * 68];
    __shared__ float plds[160 * 16];

    int bh = blockIdx.x;
    int b = bh >> 2, h = bh & 3;
    int tid = threadIdx.x;
    int jt = tid & 15;
    int ig = tid >> 4;  // 0..15

    const float* qb = q    + (size_t)bh * Dd * Ss;
    const float* kb = ksub + (size_t)bh * ALLOCC * Ss;
    const float* vb = vsub + (size_t)bh * ALLOCC * Ss;

    float acc[10];
    #pragma unroll
    for (int r = 0; r < 10; ++r) acc[r] = 0.f;

    // ---- phase 1: dot[i][jt] = sum_s q[i,s] * k[jt,s] ----
    for (int s0 = 0; s0 < Ss; s0 += 64) {
        for (int e = tid; e < 160 * 64; e += 256) {
            int i = e >> 6, s = e & 63;
            qv[i * 68 + s] = qb[(size_t)i * Ss + s0 + s];
        }
        for (int e = tid; e < 16 * 64; e += 256) {
            int j = e >> 6, s = e & 63;
            klds[j * 68 + s] = kb[(size_t)j * Ss + s0 + s];
        }
        __syncthreads();
        for (int s = 0; s < 64; s += 4) {
            float4 kq = *(const float4*)&klds[jt * 68 + s];
            #pragma unroll
            for (int r = 0; r < 10; ++r) {
                int i = ig + 16 * r;
                float4 qq = *(const float4*)&qv[i * 68 + s];
                acc[r] += qq.x * kq.x + qq.y * kq.y + qq.z * kq.z + qq.w * kq.w;
            }
        }
        __syncthreads();
    }

    // ---- softmax over the 16 allowed columns (shfl within 16-lane groups) ----
    int ycol = y[b] * ALLOCC;
    #pragma unroll
    for (int r = 0; r < 10; ++r) {
        float d = acc[r] * ATT_SCALE;
        float mx = d;
        for (int m = 8; m; m >>= 1) mx = fmaxf(mx, __shfl_xor(mx, m, 16));
        float e = __expf(d - mx);
        float sum = e;
        for (int m = 8; m; m >>= 1) sum += __shfl_xor(sum, m, 16);
        float p = e / sum;
        int i = ig + 16 * r;
        plds[i * 16 + jt] = p;
        attn[((size_t)bh * Dd + i) * Dd + ycol + jt] = p;
    }
    __syncthreads();

    // ---- phase 2: o[i,s] = sum_jt p[i][jt] * v[jt,s] ----
    float* vlds = qv;  // reuse
    for (int s0 = 0; s0 < Ss; s0 += 256) {
        for (int e = tid; e < 16 * 256; e += 256) {
            int j = e >> 8, s = e & 255;
            vlds[j * 256 + s] = vb[(size_t)j * Ss + s0 + s];
        }
        __syncthreads();
        float vr[16];
        #pragma unroll
        for (int j = 0; j < 16; ++j) vr[j] = vlds[j * 256 + tid];
        float* obp = o + ((size_t)b * COUT + h * Dd) * Ss + s0 + tid;
        for (int i = 0; i < Dd; ++i) {
            const float4* p4 = (const float4*)&plds[i * 16];
            float a = 0.f;
            #pragma unroll
            for (int j4 = 0; j4 < 4; ++j4) {
                float4 pv = p4[j4];
                a += pv.x * vr[j4 * 4 + 0] + pv.y * vr[j4 * 4 + 1]
                   + pv.z * vr[j4 * 4 + 2] + pv.w * vr[j4 * 4 + 3];
            }
            obp[(size_t)i * Ss] = a;
        }
        __syncthreads();
    }
}

extern "C" void kernel_launch(void* const* d_in, const int* in_sizes, int n_in,
                              void* d_out, int out_size, void* d_ws, size_t ws_size,
                              hipStream_t stream) {
    const float* x     = (const float*)d_in[0];
    const int*   y     = (const int*)  d_in[1];
    const float* w1    = (const float*)d_in[2];
    const float* b1    = (const float*)d_in[3];
    const float* gamma = (const float*)d_in[4];
    const float* beta  = (const float*)d_in[5];
    const float* wqkv  = (const float*)d_in[6];

    float* o    = (float*)d_out;
    float* attn = o + (size_t)Bn * COUT * Ss;

    float* ws     = (float*)d_ws;
    float* conv   = ws;                                    // 41,943,040 f
    float* q      = conv + (size_t)Bn * COUT * Ss;         // 41,943,040 f
    float* ks     = q    + (size_t)Bn * NH * Dd * Ss;      //  4,194,304 f
    float* vs     = ks   + (size_t)Bn * NH * ALLOCC * Ss;  //  4,194,304 f
    float* scaleC = vs   + (size_t)Bn * NH * ALLOCC * Ss;  //        640 f
    float* shiftC = scaleC + COUT;                         //        640 f

    conv3x3_k<<<Bn * COUT * Ss / 256, 256, 0, stream>>>(x, w1, b1, conv);
    bnstats_k<<<COUT, 256, 0, stream>>>(conv, gamma, beta, scaleC, shiftC);
    zerof_k<<<(Bn * NH * Dd * Dd + 255) / 256, 256, 0, stream>>>(attn, Bn * NH * Dd * Dd);
    qkv_k<<<(size_t)Bn * NH * 192 * Ss / 256, 256, 0, stream>>>(conv, wqkv, scaleC, shiftC, y, q, ks, vs);
    attn_k<<<Bn * NH, 256, 0, stream>>>(q, ks, vs, y, o, attn);
}

// Round 2
// 1157.703 us; speedup vs baseline: 4.8278x; 4.8278x over previous
//
#include <hip/hip_runtime.h>
#include <math.h>

namespace {
constexpr int Bn    = 64;
constexpr int CIN   = 320;
constexpr int COUT  = 640;
constexpr int CIN_G = 32;   // 320/10
constexpr int COUT_G= 64;   // 640/10
constexpr int NH    = 4;
constexpr int Dd    = 160;
constexpr int ALLOCC= 16;
constexpr int Hh    = 32, Wh = 32;
constexpr int Ss    = 1024; // 32*32
constexpr float ATT_SCALE = 0.0395284707521047f; // 640^-0.5
}

// ---------------- K1: grouped conv3x3 + bias (LDS-tiled, register-blocked) ----
// Block = 64 threads (1 wave). blockIdx.x = b*10+g, blockIdx.y = oc-quad (16).
// Thread: 4 oc x (2 hy x 8 wx) outputs. Weights are block-uniform -> SGPRs.
__global__ __launch_bounds__(64) void conv3x3_k(
    const float* __restrict__ x, const float* __restrict__ w1,
    const float* __restrict__ b1, float* __restrict__ out) {
    __shared__ float xlds[2 * 34 * 36];   // 2 ic x 34 rows x 36 cols (padded halo)

    int bg = blockIdx.x;
    int b = bg / 10, g = bg % 10;
    int oc0 = blockIdx.y * 4;             // oc within group, 0..60
    int tid = threadIdx.x;
    int hy0 = (tid >> 2) * 2;             // 0,2,..,30
    int wx0 = (tid & 3) * 8;              // 0,8,16,24

    const float* xb = x  + ((size_t)b * CIN + g * CIN_G) * Ss;
    const float* wg = w1 + (size_t)(g * COUT_G + oc0) * (CIN_G * 9);

    float acc[4][2][8];
    #pragma unroll
    for (int j = 0; j < 4; ++j)
        #pragma unroll
        for (int oy = 0; oy < 2; ++oy)
            #pragma unroll
            for (int sp = 0; sp < 8; ++sp) acc[j][oy][sp] = 0.f;

    for (int ci = 0; ci < 16; ++ci) {     // 16 chunks of 2 ic
        // ---- stage 2 x 34 x 36 tile (zero halo), float4 LDS writes ----
        for (int e4 = tid; e4 < 612; e4 += 64) {
            int e = e4 * 4;
            int icl = e / 1224;
            int rem = e - icl * 1224;
            int r = rem / 36, c0 = rem - r * 36;
            int xr = r - 1;
            float4 v;
            float* vp = &v.x;
            #pragma unroll
            for (int u = 0; u < 4; ++u) {
                int xc = c0 + u - 1;
                vp[u] = (xr >= 0 && xr < Hh && xc >= 0 && xc < Wh)
                        ? xb[((size_t)(ci * 2 + icl)) * Ss + xr * Wh + xc] : 0.f;
            }
            *(float4*)&xlds[e] = v;
        }
        __syncthreads();

        #pragma unroll
        for (int icl = 0; icl < 2; ++icl) {
            int ic = ci * 2 + icl;
            // weights: block-uniform address -> scalar loads (SGPR)
            float wv[36];
            #pragma unroll
            for (int j = 0; j < 4; ++j)
                #pragma unroll
                for (int tp = 0; tp < 9; ++tp)
                    wv[j * 9 + tp] = wg[j * (CIN_G * 9) + ic * 9 + tp];

            #pragma unroll
            for (int rr = 0; rr < 4; ++rr) {
                int base = icl * 1224 + (hy0 + rr) * 36 + wx0;
                float4 xa = *(const float4*)&xlds[base];
                float4 xb4 = *(const float4*)&xlds[base + 4];
                float4 xc4 = *(const float4*)&xlds[base + 8];
                float xr_[12] = {xa.x, xa.y, xa.z, xa.w,
                                 xb4.x, xb4.y, xb4.z, xb4.w,
                                 xc4.x, xc4.y, xc4.z, xc4.w};
                #pragma unroll
                for (int oy = 0; oy < 2; ++oy) {
                    int dy = rr - oy;
                    if (dy < 0 || dy > 2) continue;
                    #pragma unroll
                    for (int j = 0; j < 4; ++j)
                        #pragma unroll
                        for (int dx = 0; dx < 3; ++dx) {
                            float w_ = wv[j * 9 + dy * 3 + dx];
                            #pragma unroll
                            for (int sp = 0; sp < 8; ++sp)
                                acc[j][oy][sp] = fmaf(w_, xr_[sp + dx], acc[j][oy][sp]);
                        }
                }
            }
        }
        __syncthreads();
    }

    // ---- store ----
    #pragma unroll
    for (int j = 0; j < 4; ++j) {
        float bias = b1[g * COUT_G + oc0 + j];
        #pragma unroll
        for (int oy = 0; oy < 2; ++oy) {
            size_t base = ((size_t)b * COUT + g * COUT_G + oc0 + j) * Ss
                        + (hy0 + oy) * Wh + wx0;
            float4 v0 = {acc[j][oy][0] + bias, acc[j][oy][1] + bias,
                         acc[j][oy][2] + bias, acc[j][oy][3] + bias};
            float4 v1 = {acc[j][oy][4] + bias, acc[j][oy][5] + bias,
                         acc[j][oy][6] + bias, acc[j][oy][7] + bias};
            *(float4*)&out[base]     = v0;
            *(float4*)&out[base + 4] = v1;
        }
    }
}

// ---------------- K2: BN stats -> scale/shift ----------------
__global__ __launch_bounds__(256) void bnstats_k(
    const float* __restrict__ conv, const float* __restrict__ gamma,
    const float* __restrict__ beta, float* __restrict__ scaleC,
    float* __restrict__ shiftC) {
    int c = blockIdx.x;
    double s = 0.0, s2 = 0.0;
    for (int e = threadIdx.x; e < Bn * Ss; e += 256) {
        int b = e >> 10, sp = e & 1023;
        float v = conv[((size_t)b * COUT + c) * Ss + sp];
        s += v; s2 += (double)v * v;
    }
    __shared__ double rs[256], rs2[256];
    rs[threadIdx.x] = s; rs2[threadIdx.x] = s2;
    __syncthreads();
    for (int off = 128; off > 0; off >>= 1) {
        if (threadIdx.x < off) { rs[threadIdx.x] += rs[threadIdx.x + off]; rs2[threadIdx.x] += rs2[threadIdx.x + off]; }
        __syncthreads();
    }
    if (threadIdx.x == 0) {
        double mean = rs[0] / (Bn * Ss);
        double var  = rs2[0] / (Bn * Ss) - mean * mean;
        float sc = gamma[c] * rsqrtf((float)var + 1e-5f);
        scaleC[c] = sc;
        shiftC[c] = beta[c] - (float)mean * sc;
    }
}

// ---------------- K3: zero attn region ----------------
__global__ __launch_bounds__(256) void zerof_k(float* __restrict__ p, int n) {
    int i = blockIdx.x * 256 + threadIdx.x;
    if (i < n) p[i] = 0.f;
}

// ---------------- K4: BN+ReLU fused grouped 1x1 -> q, k_sub, v_sub ----------
// blockIdx.x = (b*4+h)*12+qg, blockIdx.y = quad-in-group (4). Block 256 thr.
// Each thread: 4 s-tiles x 4 output rows; weights block-uniform -> SGPRs.
__global__ __launch_bounds__(256) void qkv_k(
    const float* __restrict__ conv, const float* __restrict__ wqkv,
    const float* __restrict__ scaleC, const float* __restrict__ shiftC,
    const int* __restrict__ y,
    float* __restrict__ q, float* __restrict__ ksub, float* __restrict__ vsub) {
    int bhq = blockIdx.x;
    int qg = bhq % 12;
    int bh = bhq / 12;
    int h = bh & 3, b = bh >> 2;
    int t0 = (qg * 4 + blockIdx.y) * 4;   // 0,4,...,188
    int tid = threadIdx.x;

    int c_out0; float* dst;
    if (t0 < 160) {
        c_out0 = h * Dd + t0;
        dst = q + ((size_t)bh * Dd + t0) * Ss;
    } else if (t0 < 176) {
        int j0 = t0 - 160; int d0 = y[b] * ALLOCC + j0;
        c_out0 = 640 + h * Dd + d0;
        dst = ksub + ((size_t)bh * ALLOCC + j0) * Ss;
    } else {
        int j0 = t0 - 176; int d0 = y[b] * ALLOCC + j0;
        c_out0 = 1280 + h * Dd + d0;
        dst = vsub + ((size_t)bh * ALLOCC + j0) * Ss;
    }
    int g = c_out0 / 192;                 // qkv feature group
    const float* cb = conv + ((size_t)b * COUT + g * COUT_G) * Ss;
    const float* wb = wqkv + (size_t)c_out0 * COUT_G;

    float acc[4][4];
    #pragma unroll
    for (int st = 0; st < 4; ++st)
        #pragma unroll
        for (int r = 0; r < 4; ++r) acc[st][r] = 0.f;

    for (int c = 0; c < COUT_G; ++c) {
        int ch = g * COUT_G + c;
        float sc = scaleC[ch], sh = shiftC[ch];
        float w0 = wb[c], w1_ = wb[COUT_G + c], w2 = wb[2 * COUT_G + c], w3 = wb[3 * COUT_G + c];
        #pragma unroll
        for (int st = 0; st < 4; ++st) {
            float cv = cb[(size_t)c * Ss + st * 256 + tid];
            cv = fmaxf(fmaf(cv, sc, sh), 0.f);
            acc[st][0] = fmaf(w0, cv, acc[st][0]);
            acc[st][1] = fmaf(w1_, cv, acc[st][1]);
            acc[st][2] = fmaf(w2, cv, acc[st][2]);
            acc[st][3] = fmaf(w3, cv, acc[st][3]);
        }
    }
    #pragma unroll
    for (int r = 0; r < 4; ++r)
        #pragma unroll
        for (int st = 0; st < 4; ++st)
            dst[(size_t)r * Ss + st * 256 + tid] = acc[st][r];
}

// ---------------- K5: attention per (b,h) block ----------------
__global__ __launch_bounds__(256) void attn_k(
    const float* __restrict__ q, const float* __restrict__ ksub,
    const float* __restrict__ vsub, const int* __restrict__ y,
    float* __restrict__ o, float* __restrict__ attn) {
    __shared__ float qv[160 * 68];   // phase1: q tile [160][68]; phase2: v tile [16][256]
    __shared__ float klds[16 * 68];
    __shared__ float plds[160 * 16];

    int bh = blockIdx.x;
    int b = bh >> 2, h = bh & 3;
    int tid = threadIdx.x;
    int jt = tid & 15;
    int ig = tid >> 4;  // 0..15

    const float* qb = q    + (size_t)bh * Dd * Ss;
    const float* kb = ksub + (size_t)bh * ALLOCC * Ss;
    const float* vb = vsub + (size_t)bh * ALLOCC * Ss;

    float acc[10];
    #pragma unroll
    for (int r = 0; r < 10; ++r) acc[r] = 0.f;

    // ---- phase 1: dot[i][jt] = sum_s q[i,s] * k[jt,s] ----
    for (int s0 = 0; s0 < Ss; s0 += 64) {
        for (int e = tid; e < 160 * 64; e += 256) {
            int i = e >> 6, s = e & 63;
            qv[i * 68 + s] = qb[(size_t)i * Ss + s0 + s];
        }
        for (int e = tid; e < 16 * 64; e += 256) {
            int j = e >> 6, s = e & 63;
            klds[j * 68 + s] = kb[(size_t)j * Ss + s0 + s];
        }
        __syncthreads();
        for (int s = 0; s < 64; s += 4) {
            float4 kq = *(const float4*)&klds[jt * 68 + s];
            #pragma unroll
            for (int r = 0; r < 10; ++r) {
                int i = ig + 16 * r;
                float4 qq = *(const float4*)&qv[i * 68 + s];
                acc[r] += qq.x * kq.x + qq.y * kq.y + qq.z * kq.z + qq.w * kq.w;
            }
        }
        __syncthreads();
    }

    // ---- softmax over the 16 allowed columns (shfl within 16-lane groups) ----
    int ycol = y[b] * ALLOCC;
    #pragma unroll
    for (int r = 0; r < 10; ++r) {
        float d = acc[r] * ATT_SCALE;
        float mx = d;
        for (int m = 8; m; m >>= 1) mx = fmaxf(mx, __shfl_xor(mx, m, 16));
        float e = __expf(d - mx);
        float sum = e;
        for (int m = 8; m; m >>= 1) sum += __shfl_xor(sum, m, 16);
        float p = e / sum;
        int i = ig + 16 * r;
        plds[i * 16 + jt] = p;
        attn[((size_t)bh * Dd + i) * Dd + ycol + jt] = p;
    }
    __syncthreads();

    // ---- phase 2: o[i,s] = sum_jt p[i][jt] * v[jt,s] ----
    float* vlds = qv;  // reuse
    for (int s0 = 0; s0 < Ss; s0 += 256) {
        for (int e = tid; e < 16 * 256; e += 256) {
            int j = e >> 8, s = e & 255;
            vlds[j * 256 + s] = vb[(size_t)j * Ss + s0 + s];
        }
        __syncthreads();
        float vr[16];
        #pragma unroll
        for (int j = 0; j < 16; ++j) vr[j] = vlds[j * 256 + tid];
        float* obp = o + ((size_t)b * COUT + h * Dd) * Ss + s0 + tid;
        for (int i = 0; i < Dd; ++i) {
            const float4* p4 = (const float4*)&plds[i * 16];
            float a = 0.f;
            #pragma unroll
            for (int j4 = 0; j4 < 4; ++j4) {
                float4 pv = p4[j4];
                a += pv.x * vr[j4 * 4 + 0] + pv.y * vr[j4 * 4 + 1]
                   + pv.z * vr[j4 * 4 + 2] + pv.w * vr[j4 * 4 + 3];
            }
            obp[(size_t)i * Ss] = a;
        }
        __syncthreads();
    }
}

extern "C" void kernel_launch(void* const* d_in, const int* in_sizes, int n_in,
                              void* d_out, int out_size, void* d_ws, size_t ws_size,
                              hipStream_t stream) {
    const float* x     = (const float*)d_in[0];
    const int*   y     = (const int*)  d_in[1];
    const float* w1    = (const float*)d_in[2];
    const float* b1    = (const float*)d_in[3];
    const float* gamma = (const float*)d_in[4];
    const float* beta  = (const float*)d_in[5];
    const float* wqkv  = (const float*)d_in[6];

    float* o    = (float*)d_out;
    float* attn = o + (size_t)Bn * COUT * Ss;

    float* ws     = (float*)d_ws;
    float* conv   = ws;                                    // 41,943,040 f
    float* q      = conv + (size_t)Bn * COUT * Ss;         // 41,943,040 f
    float* ks     = q    + (size_t)Bn * NH * Dd * Ss;      //  4,194,304 f
    float* vs     = ks   + (size_t)Bn * NH * ALLOCC * Ss;  //  4,194,304 f
    float* scaleC = vs   + (size_t)Bn * NH * ALLOCC * Ss;  //        640 f
    float* shiftC = scaleC + COUT;                         //        640 f

    conv3x3_k<<<dim3(Bn * 10, 16), 64, 0, stream>>>(x, w1, b1, conv);
    bnstats_k<<<COUT, 256, 0, stream>>>(conv, gamma, beta, scaleC, shiftC);
    zerof_k<<<(Bn * NH * Dd * Dd + 255) / 256, 256, 0, stream>>>(attn, Bn * NH * Dd * Dd);
    qkv_k<<<dim3(Bn * NH * 12, 4), 256, 0, stream>>>(conv, wqkv, scaleC, shiftC, y, q, ks, vs);
    attn_k<<<Bn * NH, 256, 0, stream>>>(q, ks, vs, y, o, attn);
}

// Round 3
// 759.997 us; speedup vs baseline: 7.3542x; 1.5233x over previous
//
#include <hip/hip_runtime.h>
#include <math.h>

namespace {
constexpr int Bn    = 64;
constexpr int CIN   = 320;
constexpr int COUT  = 640;
constexpr int CIN_G = 32;   // 320/10
constexpr int COUT_G= 64;   // 640/10
constexpr int NH    = 4;
constexpr int Dd    = 160;
constexpr int ALLOCC= 16;
constexpr int Hh    = 32, Wh = 32;
constexpr int Ss    = 1024; // 32*32
constexpr float ATT_SCALE = 0.0395284707521047f; // 640^-0.5
// conv LDS tile: 2 ic x 34 rows x 40 cols (stride 40, XOR-4 swizzle by (row>>1)&1)
constexpr int LROW = 40;
constexpr int LIC  = 34 * LROW;  // 1360
}

// ---------------- K1: grouped conv3x3 + bias + BN partial sums ----------------
// Block = 64 threads (1 wave). blockIdx.x = b*10+g, blockIdx.y = oc-quad (16).
// Thread: 4 oc x (2 hy x 8 wx) outputs. Weights block-uniform -> SGPRs.
__global__ __launch_bounds__(64) void conv3x3_k(
    const float* __restrict__ x, const float* __restrict__ w1,
    const float* __restrict__ b1, float* __restrict__ out,
    double* __restrict__ statS, double* __restrict__ statS2) {
    __shared__ float xlds[2 * LIC];

    int bg = blockIdx.x;
    int b = bg / 10, g = bg % 10;
    int oc0 = blockIdx.y * 4;             // oc within group, 0..60
    int tid = threadIdx.x;
    int hy0 = (tid >> 2) * 2;             // 0,2,..,30
    int wx0 = (tid & 3) * 8;              // 0,8,16,24

    const float* xb = x  + ((size_t)b * CIN + g * CIN_G) * Ss;
    const float* wg = w1 + (size_t)(g * COUT_G + oc0) * (CIN_G * 9);

    float acc[4][2][8];
    #pragma unroll
    for (int j = 0; j < 4; ++j)
        #pragma unroll
        for (int oy = 0; oy < 2; ++oy)
            #pragma unroll
            for (int sp = 0; sp < 8; ++sp) acc[j][oy][sp] = 0.f;

    for (int ci = 0; ci < 16; ++ci) {     // 16 chunks of 2 ic
        // ---- stage: task = (icl, r) padded row; swizzled float4 stores ----
        for (int t = tid; t < 68; t += 64) {
            int icl = t / 34, r = t - icl * 34;
            int sbase = icl * LIC + r * LROW;
            int xorv = ((r >> 1) & 1) * 4;
            if (r == 0 || r == 33) {
                float4 z = {0.f, 0.f, 0.f, 0.f};
                #pragma unroll
                for (int g4 = 0; g4 < 9; ++g4)
                    *(float4*)&xlds[sbase + ((g4 * 4) ^ xorv)] = z;
            } else {
                const float* xrow = xb + ((size_t)(ci * 2 + icl)) * Ss + (r - 1) * Wh;
                float4 rx[8];
                #pragma unroll
                for (int k = 0; k < 8; ++k) rx[k] = *(const float4*)&xrow[4 * k];
                float4 gq;
                gq = make_float4(0.f, rx[0].x, rx[0].y, rx[0].z);
                *(float4*)&xlds[sbase + (0 ^ xorv)] = gq;
                #pragma unroll
                for (int k = 1; k < 8; ++k) {
                    gq = make_float4(rx[k-1].w, rx[k].x, rx[k].y, rx[k].z);
                    *(float4*)&xlds[sbase + ((4 * k) ^ xorv)] = gq;
                }
                gq = make_float4(rx[7].w, 0.f, 0.f, 0.f);
                *(float4*)&xlds[sbase + (32 ^ xorv)] = gq;
            }
        }
        __syncthreads();

        #pragma unroll
        for (int icl = 0; icl < 2; ++icl) {
            int ic = ci * 2 + icl;
            float wv[36];
            #pragma unroll
            for (int j = 0; j < 4; ++j)
                #pragma unroll
                for (int tp = 0; tp < 9; ++tp)
                    wv[j * 9 + tp] = wg[j * (CIN_G * 9) + ic * 9 + tp];

            #pragma unroll
            for (int rr = 0; rr < 4; ++rr) {
                int row = hy0 + rr;
                int base = icl * LIC + row * LROW;
                int xorv = ((row >> 1) & 1) * 4;
                float4 xa  = *(const float4*)&xlds[base + ( wx0       ^ xorv)];
                float4 xb4 = *(const float4*)&xlds[base + ((wx0 +  4) ^ xorv)];
                float4 xc4 = *(const float4*)&xlds[base + ((wx0 +  8) ^ xorv)];
                float xr_[12] = {xa.x, xa.y, xa.z, xa.w,
                                 xb4.x, xb4.y, xb4.z, xb4.w,
                                 xc4.x, xc4.y, xc4.z, xc4.w};
                #pragma unroll
                for (int oy = 0; oy < 2; ++oy) {
                    int dy = rr - oy;
                    if (dy < 0 || dy > 2) continue;
                    #pragma unroll
                    for (int j = 0; j < 4; ++j)
                        #pragma unroll
                        for (int dx = 0; dx < 3; ++dx) {
                            float w_ = wv[j * 9 + dy * 3 + dx];
                            #pragma unroll
                            for (int sp = 0; sp < 8; ++sp)
                                acc[j][oy][sp] = fmaf(w_, xr_[sp + dx], acc[j][oy][sp]);
                        }
                }
            }
        }
        __syncthreads();
    }

    // ---- store + per-oc BN partial sums ----
    float ps[4], ps2[4];
    #pragma unroll
    for (int j = 0; j < 4; ++j) {
        float bias = b1[g * COUT_G + oc0 + j];
        ps[j] = 0.f; ps2[j] = 0.f;
        #pragma unroll
        for (int oy = 0; oy < 2; ++oy) {
            size_t base = ((size_t)b * COUT + g * COUT_G + oc0 + j) * Ss
                        + (hy0 + oy) * Wh + wx0;
            float4 v0 = {acc[j][oy][0] + bias, acc[j][oy][1] + bias,
                         acc[j][oy][2] + bias, acc[j][oy][3] + bias};
            float4 v1 = {acc[j][oy][4] + bias, acc[j][oy][5] + bias,
                         acc[j][oy][6] + bias, acc[j][oy][7] + bias};
            *(float4*)&out[base]     = v0;
            *(float4*)&out[base + 4] = v1;
            ps[j]  += (v0.x + v0.y) + (v0.z + v0.w) + (v1.x + v1.y) + (v1.z + v1.w);
            ps2[j] += v0.x*v0.x + v0.y*v0.y + v0.z*v0.z + v0.w*v0.w
                    + v1.x*v1.x + v1.y*v1.y + v1.z*v1.z + v1.w*v1.w;
        }
    }
    #pragma unroll
    for (int m = 32; m; m >>= 1)
        #pragma unroll
        for (int j = 0; j < 4; ++j) {
            ps[j]  += __shfl_xor(ps[j],  m);
            ps2[j] += __shfl_xor(ps2[j], m);
        }
    if (tid == 0)
        #pragma unroll
        for (int j = 0; j < 4; ++j) {
            int oc = g * COUT_G + oc0 + j;
            atomicAdd(&statS[oc],  (double)ps[j]);
            atomicAdd(&statS2[oc], (double)ps2[j]);
        }
}

// ---------------- K2: finalize BN scale/shift ----------------
__global__ __launch_bounds__(256) void finalize_k(
    const double* __restrict__ statS, const double* __restrict__ statS2,
    const float* __restrict__ gamma, const float* __restrict__ beta,
    float* __restrict__ scaleC, float* __restrict__ shiftC) {
    int c = blockIdx.x * 256 + threadIdx.x;
    if (c >= COUT) return;
    double N = (double)Bn * Ss;
    double mean = statS[c] / N;
    double var  = statS2[c] / N - mean * mean;
    float sc = gamma[c] * rsqrtf((float)(var + 1e-5));
    scaleC[c] = sc;
    shiftC[c] = beta[c] - (float)mean * sc;
}

// ---------------- K3: zero attn region ----------------
__global__ __launch_bounds__(256) void zerof_k(float* __restrict__ p, int n) {
    int i = blockIdx.x * 256 + threadIdx.x;
    if (i < n) p[i] = 0.f;
}

// ---------------- K4: BN+ReLU fused grouped 1x1 (group-centric) ----------
// grid = (b*10+g, s-quarter). 256 threads; thread owns one s column.
// conv channels held in registers; weights block-uniform -> SGPR loads.
__global__ __launch_bounds__(256) void qkv_k(
    const float* __restrict__ conv, const float* __restrict__ wqkv,
    const float* __restrict__ scaleC, const float* __restrict__ shiftC,
    const int* __restrict__ y,
    float* __restrict__ q, float* __restrict__ ksub, float* __restrict__ vsub) {
    int bg = blockIdx.x;
    int b = bg / 10, g = bg % 10;
    int s = blockIdx.y * 256 + threadIdx.x;
    int yv = __builtin_amdgcn_readfirstlane(y[b]);

    const float* cb = conv + ((size_t)b * COUT + g * COUT_G) * Ss + s;
    float t[64];
    #pragma unroll
    for (int c = 0; c < 64; ++c) {
        float v = cb[(size_t)c * Ss];
        t[c] = fmaxf(fmaf(v, scaleC[g * COUT_G + c], shiftC[g * COUT_G + c]), 0.f);
    }

    // ---- q rows in this group ----
    int q0 = g * 192;
    int q1 = q0 + 192 < COUT ? q0 + 192 : COUT;
    for (int r0 = q0; r0 < q1; r0 += 4) {
        const float* wr = wqkv + (size_t)r0 * COUT_G;
        float a0 = 0.f, a1 = 0.f, a2 = 0.f, a3 = 0.f;
        #pragma unroll
        for (int c = 0; c < 64; ++c) {
            float tv = t[c];
            a0 = fmaf(wr[c],       tv, a0);
            a1 = fmaf(wr[64 + c],  tv, a1);
            a2 = fmaf(wr[128 + c], tv, a2);
            a3 = fmaf(wr[192 + c], tv, a3);
        }
        int h = r0 / Dd, d = r0 - h * Dd;   // 4 rows never cross a head (4|160)
        float* dq = q + (((size_t)(b * NH + h)) * Dd + d) * Ss + s;
        dq[0] = a0; dq[Ss] = a1; dq[2 * Ss] = a2; dq[3 * Ss] = a3;
    }
    // ---- k rows (16 per head, contiguous, never cross group: 16 | base) ----
    for (int h = 0; h < NH; ++h) {
        int base = COUT + h * Dd + yv * ALLOCC;
        if (base / 192 != g) continue;
        for (int j0 = 0; j0 < 16; j0 += 4) {
            const float* wr = wqkv + (size_t)(base + j0) * COUT_G;
            float a0 = 0.f, a1 = 0.f, a2 = 0.f, a3 = 0.f;
            #pragma unroll
            for (int c = 0; c < 64; ++c) {
                float tv = t[c];
                a0 = fmaf(wr[c],       tv, a0);
                a1 = fmaf(wr[64 + c],  tv, a1);
                a2 = fmaf(wr[128 + c], tv, a2);
                a3 = fmaf(wr[192 + c], tv, a3);
            }
            float* dk = ksub + (((size_t)(b * NH + h)) * ALLOCC + j0) * Ss + s;
            dk[0] = a0; dk[Ss] = a1; dk[2 * Ss] = a2; dk[3 * Ss] = a3;
        }
    }
    // ---- v rows ----
    for (int h = 0; h < NH; ++h) {
        int base = 2 * COUT + h * Dd + yv * ALLOCC;
        if (base / 192 != g) continue;
        for (int j0 = 0; j0 < 16; j0 += 4) {
            const float* wr = wqkv + (size_t)(base + j0) * COUT_G;
            float a0 = 0.f, a1 = 0.f, a2 = 0.f, a3 = 0.f;
            #pragma unroll
            for (int c = 0; c < 64; ++c) {
                float tv = t[c];
                a0 = fmaf(wr[c],       tv, a0);
                a1 = fmaf(wr[64 + c],  tv, a1);
                a2 = fmaf(wr[128 + c], tv, a2);
                a3 = fmaf(wr[192 + c], tv, a3);
            }
            float* dv = vsub + (((size_t)(b * NH + h)) * ALLOCC + j0) * Ss + s;
            dv[0] = a0; dv[Ss] = a1; dv[2 * Ss] = a2; dv[3 * Ss] = a3;
        }
    }
}

// ---------------- K5: attention per (b,h) block ----------------
__global__ __launch_bounds__(256) void attn_k(
    const float* __restrict__ q, const float* __restrict__ ksub,
    const float* __restrict__ vsub, const int* __restrict__ y,
    float* __restrict__ o, float* __restrict__ attn) {
    __shared__ float qv[160 * 68];   // phase1: q tile [160][68]; phase2: v tile [16][256]
    __shared__ float klds[16 * 68];
    __shared__ float plds[160 * 16];

    int bh = blockIdx.x;
    int b = bh >> 2, h = bh & 3;
    int tid = threadIdx.x;
    int jt = tid & 15;
    int ig = tid >> 4;  // 0..15

    const float* qb = q    + (size_t)bh * Dd * Ss;
    const float* kb = ksub + (size_t)bh * ALLOCC * Ss;
    const float* vb = vsub + (size_t)bh * ALLOCC * Ss;

    float acc[10];
    #pragma unroll
    for (int r = 0; r < 10; ++r) acc[r] = 0.f;

    // ---- phase 1: dot[i][jt] = sum_s q[i,s] * k[jt,s] ----
    for (int s0 = 0; s0 < Ss; s0 += 64) {
        for (int e = tid; e < 160 * 64; e += 256) {
            int i = e >> 6, s = e & 63;
            qv[i * 68 + s] = qb[(size_t)i * Ss + s0 + s];
        }
        for (int e = tid; e < 16 * 64; e += 256) {
            int j = e >> 6, s = e & 63;
            klds[j * 68 + s] = kb[(size_t)j * Ss + s0 + s];
        }
        __syncthreads();
        for (int s = 0; s < 64; s += 4) {
            float4 kq = *(const float4*)&klds[jt * 68 + s];
            #pragma unroll
            for (int r = 0; r < 10; ++r) {
                int i = ig + 16 * r;
                float4 qq = *(const float4*)&qv[i * 68 + s];
                acc[r] += qq.x * kq.x + qq.y * kq.y + qq.z * kq.z + qq.w * kq.w;
            }
        }
        __syncthreads();
    }

    // ---- softmax over the 16 allowed columns (shfl within 16-lane groups) ----
    int ycol = y[b] * ALLOCC;
    #pragma unroll
    for (int r = 0; r < 10; ++r) {
        float d = acc[r] * ATT_SCALE;
        float mx = d;
        for (int m = 8; m; m >>= 1) mx = fmaxf(mx, __shfl_xor(mx, m, 16));
        float e = __expf(d - mx);
        float sum = e;
        for (int m = 8; m; m >>= 1) sum += __shfl_xor(sum, m, 16);
        float p = e / sum;
        int i = ig + 16 * r;
        plds[i * 16 + jt] = p;
        attn[((size_t)bh * Dd + i) * Dd + ycol + jt] = p;
    }
    __syncthreads();

    // ---- phase 2: o[i,s] = sum_jt p[i][jt] * v[jt,s] ----
    float* vlds = qv;  // reuse
    for (int s0 = 0; s0 < Ss; s0 += 256) {
        for (int e = tid; e < 16 * 256; e += 256) {
            int j = e >> 8, s = e & 255;
            vlds[j * 256 + s] = vb[(size_t)j * Ss + s0 + s];
        }
        __syncthreads();
        float vr[16];
        #pragma unroll
        for (int j = 0; j < 16; ++j) vr[j] = vlds[j * 256 + tid];
        float* obp = o + ((size_t)b * COUT + h * Dd) * Ss + s0 + tid;
        for (int i = 0; i < Dd; ++i) {
            const float4* p4 = (const float4*)&plds[i * 16];
            float a = 0.f;
            #pragma unroll
            for (int j4 = 0; j4 < 4; ++j4) {
                float4 pv = p4[j4];
                a += pv.x * vr[j4 * 4 + 0] + pv.y * vr[j4 * 4 + 1]
                   + pv.z * vr[j4 * 4 + 2] + pv.w * vr[j4 * 4 + 3];
            }
            obp[(size_t)i * Ss] = a;
        }
        __syncthreads();
    }
}

extern "C" void kernel_launch(void* const* d_in, const int* in_sizes, int n_in,
                              void* d_out, int out_size, void* d_ws, size_t ws_size,
                              hipStream_t stream) {
    const float* x     = (const float*)d_in[0];
    const int*   y     = (const int*)  d_in[1];
    const float* w1    = (const float*)d_in[2];
    const float* b1    = (const float*)d_in[3];
    const float* gamma = (const float*)d_in[4];
    const float* beta  = (const float*)d_in[5];
    const float* wqkv  = (const float*)d_in[6];

    float* o    = (float*)d_out;
    float* attn = o + (size_t)Bn * COUT * Ss;

    float* ws     = (float*)d_ws;
    float* conv   = ws;                                    // 41,943,040 f
    float* q      = conv + (size_t)Bn * COUT * Ss;         // 41,943,040 f
    float* ks     = q    + (size_t)Bn * NH * Dd * Ss;      //  4,194,304 f
    float* vs     = ks   + (size_t)Bn * NH * ALLOCC * Ss;  //  4,194,304 f
    float* scaleC = vs   + (size_t)Bn * NH * ALLOCC * Ss;  //        640 f
    float* shiftC = scaleC + COUT;                         //        640 f
    double* statS  = (double*)(shiftC + COUT);             //        640 d
    double* statS2 = statS + COUT;                         //        640 d

    hipMemsetAsync(statS, 0, 2 * COUT * sizeof(double), stream);
    conv3x3_k<<<dim3(Bn * 10, 16), 64, 0, stream>>>(x, w1, b1, conv, statS, statS2);
    finalize_k<<<(COUT + 255) / 256, 256, 0, stream>>>(statS, statS2, gamma, beta, scaleC, shiftC);
    zerof_k<<<(Bn * NH * Dd * Dd + 255) / 256, 256, 0, stream>>>(attn, Bn * NH * Dd * Dd);
    qkv_k<<<dim3(Bn * 10, 4), 256, 0, stream>>>(conv, wqkv, scaleC, shiftC, y, q, ks, vs);
    attn_k<<<Bn * NH, 256, 0, stream>>>(q, ks, vs, y, o, attn);
}

// Round 4
// 609.606 us; speedup vs baseline: 9.1684x; 1.2467x over previous
//
#include <hip/hip_runtime.h>
#include <math.h>

namespace {
constexpr int Bn    = 64;
constexpr int CIN   = 320;
constexpr int COUT  = 640;
constexpr int CIN_G = 32;   // 320/10
constexpr int COUT_G= 64;   // 640/10
constexpr int NH    = 4;
constexpr int Dd    = 160;
constexpr int ALLOCC= 16;
constexpr int Ss    = 1024; // 32*32
constexpr float ATT_SCALE = 0.0395284707521047f; // 640^-0.5

typedef float  f32x4 __attribute__((ext_vector_type(4)));
typedef int    i32x4 __attribute__((ext_vector_type(4)));

__device__ inline unsigned bf16rne(float f) {
    unsigned u = __float_as_uint(f);
    return (u + 0x7FFFu + ((u >> 16) & 1u)) >> 16;
}
__device__ inline unsigned packbf16(float a, float b) {
    return bf16rne(a) | (bf16rne(b) << 16);
}
}

// ---------------- K1: grouped conv3x3 via MFMA implicit GEMM -----------------
// One block per (b,g): C[64 oc][1024 sp] = W[64][9*32] * Xcol[9*32][1024].
// 512 threads = 8 waves; wave w computes 64oc x 128sp (4 mt x 8 nt tiles of
// 16x16, K-step = one (dy,dx) x 32 ic). x LDS: bf16 [34 r][34 c][32 ic];
// w LDS: bf16 [9 dyx][64 oc][32 ic]. Epilogue: bias + fp32 store + BN sums.
__global__ __launch_bounds__(512, 2) void conv_mfma_k(
    const float* __restrict__ x, const float* __restrict__ w1,
    const float* __restrict__ b1, float* __restrict__ out,
    double* __restrict__ statS, double* __restrict__ statS2) {
    __shared__ __align__(16) unsigned short xl[34 * 34 * 32];  // 73,984 B
    __shared__ __align__(16) unsigned short wl[9 * 64 * 32];   // 36,864 B

    int bg = blockIdx.x;
    int b = bg / 10, g = bg % 10;
    int tid = threadIdx.x;
    int wid = tid >> 6;
    int lane = tid & 63;
    int lc = lane & 15;
    int kl = (lane >> 4) * 8;

    unsigned* xl32 = (unsigned*)xl;
    unsigned* wl32 = (unsigned*)wl;

    // ---- zero x tile (covers halo) ----
    for (int e = tid; e < 34 * 34 * 32 / 8; e += 512)
        *(i32x4*)&xl[e * 8] = i32x4{0, 0, 0, 0};

    __syncthreads();

    // ---- stage x interior: unit = (ic-pair, sp) ----
    const float* xg = x + ((size_t)b * CIN + g * CIN_G) * Ss;
    for (int e = tid; e < 16 * Ss; e += 512) {
        int icp = e & 15, sp = e >> 4;
        int r = (sp >> 5) + 1, c = (sp & 31) + 1;
        float f0 = xg[(size_t)(2 * icp) * Ss + sp];
        float f1 = xg[(size_t)(2 * icp + 1) * Ss + sp];
        xl32[(r * 34 + c) * 16 + icp] = packbf16(f0, f1);
    }
    // ---- stage w: unit = (dyx, oc, ic-pair) ----
    const float* wg = w1 + (size_t)(g * COUT_G) * (CIN_G * 9);
    for (int e = tid; e < 9 * 64 * 16; e += 512) {
        int icp = e & 15, oc = (e >> 4) & 63, dyx = e >> 10;
        float f0 = wg[oc * 288 + (2 * icp) * 9 + dyx];
        float f1 = wg[oc * 288 + (2 * icp + 1) * 9 + dyx];
        wl32[(dyx * 64 + oc) * 16 + icp] = packbf16(f0, f1);
    }
    __syncthreads();

    // ---- main MFMA loop ----
    f32x4 acc[4][8];
    #pragma unroll
    for (int mt = 0; mt < 4; ++mt)
        #pragma unroll
        for (int nt = 0; nt < 8; ++nt) acc[mt][nt] = f32x4{0.f, 0.f, 0.f, 0.f};

    for (int dyx = 0; dyx < 9; ++dyx) {
        int dy = dyx / 3, dx = dyx % 3;
        const unsigned short* wbase = wl + dyx * 2048 + lc * 32 + kl;
        i32x4 af[4];
        #pragma unroll
        for (int mt = 0; mt < 4; ++mt)
            af[mt] = *(const i32x4*)(wbase + mt * 512);

        // per-lane x base: row=dy, col=dx+lc
        const unsigned short* xbase = xl + (dy * 34 + dx + lc) * 32 + kl
                                         + wid * 4 * 1088;
        #pragma unroll
        for (int nt = 0; nt < 8; ++nt) {
            i32x4 bf = *(const i32x4*)(xbase + (nt >> 1) * 1088 + (nt & 1) * 512);
            #pragma unroll
            for (int mt = 0; mt < 4; ++mt)
                asm("v_mfma_f32_16x16x32_bf16 %0, %1, %2, %0"
                    : "+v"(acc[mt][nt]) : "v"(af[mt]), "v"(bf));
        }
    }

    // ---- epilogue: bias, store fp32, BN partial sums ----
    #pragma unroll
    for (int mt = 0; mt < 4; ++mt) {
        #pragma unroll
        for (int r = 0; r < 4; ++r) {
            int ocg = mt * 16 + (lane >> 4) * 4 + r;
            float bias = b1[g * COUT_G + ocg];
            float ps = 0.f, ps2 = 0.f;
            float* orow = out + ((size_t)b * COUT + g * COUT_G + ocg) * Ss
                              + wid * 128 + lc;
            #pragma unroll
            for (int nt = 0; nt < 8; ++nt) {
                float v = acc[mt][nt][r] + bias;
                orow[nt * 16] = v;
                ps += v; ps2 += v * v;
            }
            #pragma unroll
            for (int m = 8; m; m >>= 1) {
                ps  += __shfl_xor(ps,  m, 16);
                ps2 += __shfl_xor(ps2, m, 16);
            }
            if (lc == 0) {
                atomicAdd(&statS[g * COUT_G + ocg],  (double)ps);
                atomicAdd(&statS2[g * COUT_G + ocg], (double)ps2);
            }
        }
    }
}

// ---------------- K2: finalize BN scale/shift ----------------
__global__ __launch_bounds__(256) void finalize_k(
    const double* __restrict__ statS, const double* __restrict__ statS2,
    const float* __restrict__ gamma, const float* __restrict__ beta,
    float* __restrict__ scaleC, float* __restrict__ shiftC) {
    int c = blockIdx.x * 256 + threadIdx.x;
    if (c >= COUT) return;
    double N = (double)Bn * Ss;
    double mean = statS[c] / N;
    double var  = statS2[c] / N - mean * mean;
    float sc = gamma[c] * rsqrtf((float)(var + 1e-5));
    scaleC[c] = sc;
    shiftC[c] = beta[c] - (float)mean * sc;
}

// ---------------- K3: zero attn region ----------------
__global__ __launch_bounds__(256) void zerof_k(float* __restrict__ p, int n) {
    int i = blockIdx.x * 256 + threadIdx.x;
    if (i < n) p[i] = 0.f;
}

// ---------------- K4: BN+ReLU fused grouped 1x1 (group-centric) ----------
__global__ __launch_bounds__(256) void qkv_k(
    const float* __restrict__ conv, const float* __restrict__ wqkv,
    const float* __restrict__ scaleC, const float* __restrict__ shiftC,
    const int* __restrict__ y,
    float* __restrict__ q, float* __restrict__ ksub, float* __restrict__ vsub) {
    int bg = blockIdx.x;
    int b = bg / 10, g = bg % 10;
    int s = blockIdx.y * 256 + threadIdx.x;
    int yv = __builtin_amdgcn_readfirstlane(y[b]);

    const float* cb = conv + ((size_t)b * COUT + g * COUT_G) * Ss + s;
    float t[64];
    #pragma unroll
    for (int c = 0; c < 64; ++c) {
        float v = cb[(size_t)c * Ss];
        t[c] = fmaxf(fmaf(v, scaleC[g * COUT_G + c], shiftC[g * COUT_G + c]), 0.f);
    }

    int q0 = g * 192;
    int q1 = q0 + 192 < COUT ? q0 + 192 : COUT;
    for (int r0 = q0; r0 < q1; r0 += 4) {
        const float* wr = wqkv + (size_t)r0 * COUT_G;
        float a0 = 0.f, a1 = 0.f, a2 = 0.f, a3 = 0.f;
        #pragma unroll
        for (int c = 0; c < 64; ++c) {
            float tv = t[c];
            a0 = fmaf(wr[c],       tv, a0);
            a1 = fmaf(wr[64 + c],  tv, a1);
            a2 = fmaf(wr[128 + c], tv, a2);
            a3 = fmaf(wr[192 + c], tv, a3);
        }
        int h = r0 / Dd, d = r0 - h * Dd;
        float* dq = q + (((size_t)(b * NH + h)) * Dd + d) * Ss + s;
        dq[0] = a0; dq[Ss] = a1; dq[2 * Ss] = a2; dq[3 * Ss] = a3;
    }
    for (int h = 0; h < NH; ++h) {
        int base = COUT + h * Dd + yv * ALLOCC;
        if (base / 192 != g) continue;
        for (int j0 = 0; j0 < 16; j0 += 4) {
            const float* wr = wqkv + (size_t)(base + j0) * COUT_G;
            float a0 = 0.f, a1 = 0.f, a2 = 0.f, a3 = 0.f;
            #pragma unroll
            for (int c = 0; c < 64; ++c) {
                float tv = t[c];
                a0 = fmaf(wr[c],       tv, a0);
                a1 = fmaf(wr[64 + c],  tv, a1);
                a2 = fmaf(wr[128 + c], tv, a2);
                a3 = fmaf(wr[192 + c], tv, a3);
            }
            float* dk = ksub + (((size_t)(b * NH + h)) * ALLOCC + j0) * Ss + s;
            dk[0] = a0; dk[Ss] = a1; dk[2 * Ss] = a2; dk[3 * Ss] = a3;
        }
    }
    for (int h = 0; h < NH; ++h) {
        int base = 2 * COUT + h * Dd + yv * ALLOCC;
        if (base / 192 != g) continue;
        for (int j0 = 0; j0 < 16; j0 += 4) {
            const float* wr = wqkv + (size_t)(base + j0) * COUT_G;
            float a0 = 0.f, a1 = 0.f, a2 = 0.f, a3 = 0.f;
            #pragma unroll
            for (int c = 0; c < 64; ++c) {
                float tv = t[c];
                a0 = fmaf(wr[c],       tv, a0);
                a1 = fmaf(wr[64 + c],  tv, a1);
                a2 = fmaf(wr[128 + c], tv, a2);
                a3 = fmaf(wr[192 + c], tv, a3);
            }
            float* dv = vsub + (((size_t)(b * NH + h)) * ALLOCC + j0) * Ss + s;
            dv[0] = a0; dv[Ss] = a1; dv[2 * Ss] = a2; dv[3 * Ss] = a3;
        }
    }
}

// ---------------- K5: attention per (b,h) block ----------------
__global__ __launch_bounds__(256) void attn_k(
    const float* __restrict__ q, const float* __restrict__ ksub,
    const float* __restrict__ vsub, const int* __restrict__ y,
    float* __restrict__ o, float* __restrict__ attn) {
    __shared__ float qv[160 * 68];
    __shared__ float klds[16 * 68];
    __shared__ float plds[160 * 16];

    int bh = blockIdx.x;
    int b = bh >> 2, h = bh & 3;
    int tid = threadIdx.x;
    int jt = tid & 15;
    int ig = tid >> 4;

    const float* qb = q    + (size_t)bh * Dd * Ss;
    const float* kb = ksub + (size_t)bh * ALLOCC * Ss;
    const float* vb = vsub + (size_t)bh * ALLOCC * Ss;

    float acc[10];
    #pragma unroll
    for (int r = 0; r < 10; ++r) acc[r] = 0.f;

    for (int s0 = 0; s0 < Ss; s0 += 64) {
        for (int e = tid; e < 160 * 64; e += 256) {
            int i = e >> 6, s = e & 63;
            qv[i * 68 + s] = qb[(size_t)i * Ss + s0 + s];
        }
        for (int e = tid; e < 16 * 64; e += 256) {
            int j = e >> 6, s = e & 63;
            klds[j * 68 + s] = kb[(size_t)j * Ss + s0 + s];
        }
        __syncthreads();
        for (int s = 0; s < 64; s += 4) {
            float4 kq = *(const float4*)&klds[jt * 68 + s];
            #pragma unroll
            for (int r = 0; r < 10; ++r) {
                int i = ig + 16 * r;
                float4 qq = *(const float4*)&qv[i * 68 + s];
                acc[r] += qq.x * kq.x + qq.y * kq.y + qq.z * kq.z + qq.w * kq.w;
            }
        }
        __syncthreads();
    }

    int ycol = y[b] * ALLOCC;
    #pragma unroll
    for (int r = 0; r < 10; ++r) {
        float d = acc[r] * ATT_SCALE;
        float mx = d;
        for (int m = 8; m; m >>= 1) mx = fmaxf(mx, __shfl_xor(mx, m, 16));
        float e = __expf(d - mx);
        float sum = e;
        for (int m = 8; m; m >>= 1) sum += __shfl_xor(sum, m, 16);
        float p = e / sum;
        int i = ig + 16 * r;
        plds[i * 16 + jt] = p;
        attn[((size_t)bh * Dd + i) * Dd + ycol + jt] = p;
    }
    __syncthreads();

    float* vlds = qv;
    for (int s0 = 0; s0 < Ss; s0 += 256) {
        for (int e = tid; e < 16 * 256; e += 256) {
            int j = e >> 8, s = e & 255;
            vlds[j * 256 + s] = vb[(size_t)j * Ss + s0 + s];
        }
        __syncthreads();
        float vr[16];
        #pragma unroll
        for (int j = 0; j < 16; ++j) vr[j] = vlds[j * 256 + tid];
        float* obp = o + ((size_t)b * COUT + h * Dd) * Ss + s0 + tid;
        for (int i = 0; i < Dd; ++i) {
            const float4* p4 = (const float4*)&plds[i * 16];
            float a = 0.f;
            #pragma unroll
            for (int j4 = 0; j4 < 4; ++j4) {
                float4 pv = p4[j4];
                a += pv.x * vr[j4 * 4 + 0] + pv.y * vr[j4 * 4 + 1]
                   + pv.z * vr[j4 * 4 + 2] + pv.w * vr[j4 * 4 + 3];
            }
            obp[(size_t)i * Ss] = a;
        }
        __syncthreads();
    }
}

extern "C" void kernel_launch(void* const* d_in, const int* in_sizes, int n_in,
                              void* d_out, int out_size, void* d_ws, size_t ws_size,
                              hipStream_t stream) {
    const float* x     = (const float*)d_in[0];
    const int*   y     = (const int*)  d_in[1];
    const float* w1    = (const float*)d_in[2];
    const float* b1    = (const float*)d_in[3];
    const float* gamma = (const float*)d_in[4];
    const float* beta  = (const float*)d_in[5];
    const float* wqkv  = (const float*)d_in[6];

    float* o    = (float*)d_out;
    float* attn = o + (size_t)Bn * COUT * Ss;

    float* ws     = (float*)d_ws;
    float* conv   = ws;
    float* q      = conv + (size_t)Bn * COUT * Ss;
    float* ks     = q    + (size_t)Bn * NH * Dd * Ss;
    float* vs     = ks   + (size_t)Bn * NH * ALLOCC * Ss;
    float* scaleC = vs   + (size_t)Bn * NH * ALLOCC * Ss;
    float* shiftC = scaleC + COUT;
    double* statS  = (double*)(shiftC + COUT);
    double* statS2 = statS + COUT;

    hipMemsetAsync(statS, 0, 2 * COUT * sizeof(double), stream);
    conv_mfma_k<<<Bn * 10, 512, 0, stream>>>(x, w1, b1, conv, statS, statS2);
    finalize_k<<<(COUT + 255) / 256, 256, 0, stream>>>(statS, statS2, gamma, beta, scaleC, shiftC);
    zerof_k<<<(Bn * NH * Dd * Dd + 255) / 256, 256, 0, stream>>>(attn, Bn * NH * Dd * Dd);
    qkv_k<<<dim3(Bn * 10, 4), 256, 0, stream>>>(conv, wqkv, scaleC, shiftC, y, q, ks, vs);
    attn_k<<<Bn * NH, 256, 0, stream>>>(q, ks, vs, y, o, attn);
}